// Round 2
// baseline (1496.614 us; speedup 1.0000x reference)
//
#include <hip/hip_runtime.h>
#include <math.h>

#define EMBED 128
#define SBLK 4096   // blocks for edge kernels; blockmax array size

__device__ __forceinline__ float fast_tanh(float x) {
    float ax = fabsf(x);
    float e = __expf(-2.0f * ax);         // in (0,1], no overflow
    float t = (1.0f - e) / (1.0f + e);
    return copysignf(t, x);
}

// ---------------- K1: per-edge score + per-block max ----------------
// 16 lanes per edge; each lane covers 8 floats (two float4) of the 128-dim row.
__global__ __launch_bounds__(256) void k_score(
    const float* __restrict__ ent, const float* __restrict__ rel,
    const int* __restrict__ heads, const int* __restrict__ rels,
    const int* __restrict__ tails,
    float* __restrict__ score, float* __restrict__ blockmax, int E)
{
    const int lane  = threadIdx.x & 15;
    const int group = threadIdx.x >> 4;          // 16 groups of 16 lanes
    int gid    = blockIdx.x * 16 + group;
    int stride = gridDim.x * 16;
    float lmax = -INFINITY;
    for (int e = gid; e < E; e += stride) {
        int h = heads[e], r = rels[e], t = tails[e];
        const float4* ph = (const float4*)(ent + (size_t)h * EMBED) + lane * 2;
        const float4* pt = (const float4*)(ent + (size_t)t * EMBED) + lane * 2;
        const float4* pr = (const float4*)(rel + (size_t)r * EMBED) + lane * 2;
        float s = 0.f;
        #pragma unroll
        for (int q = 0; q < 2; ++q) {
            float4 vh = ph[q], vt = pt[q], vr = pr[q];
            s += vt.x * fast_tanh(vh.x + vr.x);
            s += vt.y * fast_tanh(vh.y + vr.y);
            s += vt.z * fast_tanh(vh.z + vr.z);
            s += vt.w * fast_tanh(vh.w + vr.w);
        }
        s += __shfl_xor(s, 1, 16);
        s += __shfl_xor(s, 2, 16);
        s += __shfl_xor(s, 4, 16);
        s += __shfl_xor(s, 8, 16);
        if (lane == 0) score[e] = s;
        lmax = fmaxf(lmax, s);
    }
    __shared__ float smax[256];
    smax[threadIdx.x] = lmax;
    __syncthreads();
    for (int off = 128; off > 0; off >>= 1) {
        if ((int)threadIdx.x < off)
            smax[threadIdx.x] = fmaxf(smax[threadIdx.x], smax[threadIdx.x + off]);
        __syncthreads();
    }
    if (threadIdx.x == 0) blockmax[blockIdx.x] = smax[0];
}

// ---------------- K1b: reduce blockmax -> M ----------------
__global__ __launch_bounds__(256) void k_maxred(
    const float* __restrict__ blockmax, float* __restrict__ Mout, int n)
{
    __shared__ float smax[256];
    float m = -INFINITY;
    for (int i = threadIdx.x; i < n; i += 256) m = fmaxf(m, blockmax[i]);
    smax[threadIdx.x] = m;
    __syncthreads();
    for (int off = 128; off > 0; off >>= 1) {
        if ((int)threadIdx.x < off)
            smax[threadIdx.x] = fmaxf(smax[threadIdx.x], smax[threadIdx.x + off]);
        __syncthreads();
    }
    if (threadIdx.x == 0) Mout[0] = smax[0];
}

// ---------------- K2: exp(score - M) in place + per-head segment sum ----------------
__global__ __launch_bounds__(256) void k_exp(
    float* __restrict__ score, const int* __restrict__ heads,
    const float* __restrict__ Mptr, float* __restrict__ score_sum, int E)
{
    int e = blockIdx.x * 256 + threadIdx.x;
    if (e >= E) return;
    float p = __expf(score[e] - Mptr[0]);
    score[e] = p;                       // score buffer now holds score_exp
    atomicAdd(score_sum + heads[e], p);
}

// ---------------- K3: scatter attn * e_t into agg (fp32 atomics) ----------------
// 32 lanes per edge; each lane covers one float4 (4 atomics).
__global__ __launch_bounds__(256) void k_scatter(
    const float* __restrict__ ent, const int* __restrict__ heads,
    const int* __restrict__ tails, const float* __restrict__ score_exp,
    const float* __restrict__ score_sum, float* __restrict__ agg, int E)
{
    const int lane  = threadIdx.x & 31;
    const int group = threadIdx.x >> 5;          // 8 groups of 32 lanes
    int gid    = blockIdx.x * 8 + group;
    int stride = gridDim.x * 8;
    for (int e = gid; e < E; e += stride) {
        int h = heads[e], t = tails[e];
        float attn = score_exp[e] / (score_sum[h] + 1e-10f);
        float4 v = *((const float4*)(ent + (size_t)t * EMBED) + lane);
        float* dst = agg + (size_t)h * EMBED + lane * 4;
        atomicAdd(dst + 0, attn * v.x);
        atomicAdd(dst + 1, attn * v.y);
        atomicAdd(dst + 2, attn * v.z);
        atomicAdd(dst + 3, attn * v.w);
    }
}

// ---------------- K4: out = leaky_relu((ent + agg) @ W^T), fp32 ----------------
__global__ __launch_bounds__(256) void k_gemm(
    const float* __restrict__ ent, const float* __restrict__ W,
    const float* __restrict__ agg, float* __restrict__ out, int N)
{
    __shared__ float Wl[EMBED * EMBED];          // 64 KB: W[j][d] row-major
    for (int i = threadIdx.x; i < EMBED * EMBED; i += 256)
        Wl[i] = W[i];
    __syncthreads();

    int n = blockIdx.x * 256 + threadIdx.x;
    if (n >= N) return;

    float xr[EMBED];
    const float4* pe = (const float4*)(ent + (size_t)n * EMBED);
    const float4* pa = (const float4*)(agg + (size_t)n * EMBED);
    #pragma unroll
    for (int i = 0; i < 32; ++i) {
        float4 a = pe[i], b = pa[i];
        xr[4 * i + 0] = a.x + b.x;
        xr[4 * i + 1] = a.y + b.y;
        xr[4 * i + 2] = a.z + b.z;
        xr[4 * i + 3] = a.w + b.w;
    }
    float* orow = out + (size_t)n * EMBED;
    for (int j = 0; j < EMBED; ++j) {
        const float4* wr = (const float4*)(Wl + j * EMBED);  // wave-uniform -> LDS broadcast
        float acc = 0.f;
        #pragma unroll
        for (int i = 0; i < 32; ++i) {
            float4 w = wr[i];
            acc += xr[4 * i + 0] * w.x + xr[4 * i + 1] * w.y
                 + xr[4 * i + 2] * w.z + xr[4 * i + 3] * w.w;
        }
        orow[j] = (acc > 0.f) ? acc : 0.2f * acc;
    }
}

extern "C" void kernel_launch(void* const* d_in, const int* in_sizes, int n_in,
                              void* d_out, int out_size, void* d_ws, size_t ws_size,
                              hipStream_t stream)
{
    const float* ent   = (const float*)d_in[0];   // entity_emb  [N,128] fp32
    const float* rel   = (const float*)d_in[1];   // rel_embed   [64,128] fp32
    const float* W     = (const float*)d_in[2];   // W           [128,128] fp32
    const int*   heads = (const int*)d_in[3];
    const int*   rels  = (const int*)d_in[4];
    const int*   tails = (const int*)d_in[5];
    const int E = in_sizes[3];
    const int N = in_sizes[0] / EMBED;
    float* out = (float*)d_out;

    // ws layout (floats): agg[N*128] | score[E] (reused as score_exp) |
    //                     score_sum[N] | blockmax[SBLK] | M[1]   (~54 MB)
    float* agg       = (float*)d_ws;
    float* score     = agg + (size_t)N * EMBED;
    float* score_sum = score + E;
    float* blockmax  = score_sum + N;
    float* Mval      = blockmax + SBLK;

    hipMemsetAsync(agg, 0, (size_t)N * EMBED * sizeof(float), stream);
    hipMemsetAsync(score_sum, 0, (size_t)N * sizeof(float), stream);

    k_score<<<SBLK, 256, 0, stream>>>(ent, rel, heads, rels, tails, score, blockmax, E);
    k_maxred<<<1, 256, 0, stream>>>(blockmax, Mval, SBLK);
    k_exp<<<(E + 255) / 256, 256, 0, stream>>>(score, heads, Mval, score_sum, E);
    k_scatter<<<SBLK, 256, 0, stream>>>(ent, heads, tails, score, score_sum, agg, E);
    k_gemm<<<(N + 255) / 256, 256, 0, stream>>>(ent, W, agg, out, N);
}

// Round 3
// 707.799 us; speedup vs baseline: 2.1145x; 2.1145x over previous
//
#include <hip/hip_runtime.h>
#include <math.h>

#define EMBED 128
#define SBLK 4096   // blocks for edge kernels; blockmax array size

__device__ __forceinline__ float fast_tanh(float x) {
    float ax = fabsf(x);
    float e = __expf(-2.0f * ax);         // in (0,1], no overflow
    float t = (1.0f - e) / (1.0f + e);
    return copysignf(t, x);
}

// ---------------- K1: per-edge score + per-block max + head histogram ----------------
// 16 lanes per edge; each lane covers 8 floats (two float4) of the 128-dim row.
__global__ __launch_bounds__(256) void k_score(
    const float* __restrict__ ent, const float* __restrict__ rel,
    const int* __restrict__ heads, const int* __restrict__ rels,
    const int* __restrict__ tails,
    float* __restrict__ score, float* __restrict__ blockmax,
    int* __restrict__ cnt, int E)
{
    const int lane  = threadIdx.x & 15;
    const int group = threadIdx.x >> 4;          // 16 groups of 16 lanes
    int gid    = blockIdx.x * 16 + group;
    int stride = gridDim.x * 16;
    float lmax = -INFINITY;
    for (int e = gid; e < E; e += stride) {
        int h = heads[e], r = rels[e], t = tails[e];
        const float4* ph = (const float4*)(ent + (size_t)h * EMBED) + lane * 2;
        const float4* pt = (const float4*)(ent + (size_t)t * EMBED) + lane * 2;
        const float4* pr = (const float4*)(rel + (size_t)r * EMBED) + lane * 2;
        float s = 0.f;
        #pragma unroll
        for (int q = 0; q < 2; ++q) {
            float4 vh = ph[q], vt = pt[q], vr = pr[q];
            s += vt.x * fast_tanh(vh.x + vr.x);
            s += vt.y * fast_tanh(vh.y + vr.y);
            s += vt.z * fast_tanh(vh.z + vr.z);
            s += vt.w * fast_tanh(vh.w + vr.w);
        }
        s += __shfl_xor(s, 1, 16);
        s += __shfl_xor(s, 2, 16);
        s += __shfl_xor(s, 4, 16);
        s += __shfl_xor(s, 8, 16);
        if (lane == 0) {
            score[e] = s;
            atomicAdd(cnt + h, 1);
        }
        lmax = fmaxf(lmax, s);
    }
    __shared__ float smax[256];
    smax[threadIdx.x] = lmax;
    __syncthreads();
    for (int off = 128; off > 0; off >>= 1) {
        if ((int)threadIdx.x < off)
            smax[threadIdx.x] = fmaxf(smax[threadIdx.x], smax[threadIdx.x + off]);
        __syncthreads();
    }
    if (threadIdx.x == 0) blockmax[blockIdx.x] = smax[0];
}

// ---------------- K1b: reduce blockmax -> M ----------------
__global__ __launch_bounds__(256) void k_maxred(
    const float* __restrict__ blockmax, float* __restrict__ Mout, int n)
{
    __shared__ float smax[256];
    float m = -INFINITY;
    for (int i = threadIdx.x; i < n; i += 256) m = fmaxf(m, blockmax[i]);
    smax[threadIdx.x] = m;
    __syncthreads();
    for (int off = 128; off > 0; off >>= 1) {
        if ((int)threadIdx.x < off)
            smax[threadIdx.x] = fmaxf(smax[threadIdx.x], smax[threadIdx.x + off]);
        __syncthreads();
    }
    if (threadIdx.x == 0) Mout[0] = smax[0];
}

// ---------------- K2: single-block exclusive scan of cnt -> offs, cursor ----------------
__global__ __launch_bounds__(1024) void k_scan(
    const int* __restrict__ cnt, int* __restrict__ offs,
    int* __restrict__ cursor, int N)
{
    __shared__ int buf[1024];
    __shared__ int carry_s;
    if (threadIdx.x == 0) carry_s = 0;
    __syncthreads();
    int nch = (N + 1023) >> 10;
    for (int c = 0; c < nch; ++c) {
        int i = c * 1024 + threadIdx.x;
        int v = (i < N) ? cnt[i] : 0;
        buf[threadIdx.x] = v;
        __syncthreads();
        for (int off = 1; off < 1024; off <<= 1) {
            int x = (threadIdx.x >= (unsigned)off) ? buf[threadIdx.x - off] : 0;
            __syncthreads();
            buf[threadIdx.x] += x;
            __syncthreads();
        }
        int excl = buf[threadIdx.x] - v + carry_s;
        if (i < N) { offs[i] = excl; cursor[i] = excl; }
        __syncthreads();
        if (threadIdx.x == 1023) carry_s += buf[1023];
        __syncthreads();
    }
}

// ---------------- K3: bucket-fill: p = exp(s-M), (p, tail) -> CSR position ----------------
__global__ __launch_bounds__(256) void k_fill(
    const float* __restrict__ score, const int* __restrict__ heads,
    const int* __restrict__ tails, const float* __restrict__ Mptr,
    int* __restrict__ cursor, float* __restrict__ pval,
    int* __restrict__ tailid, int E)
{
    int e = blockIdx.x * 256 + threadIdx.x;
    if (e >= E) return;
    float p = __expf(score[e] - Mptr[0]);
    int pos = atomicAdd(cursor + heads[e], 1);
    pval[pos] = p;
    tailid[pos] = tails[e];
}

// ---------------- K4: per-head gather: agg[h] = (sum p*e_t) / (sum p + 1e-10) ----------------
// 16 lanes per head; each lane covers 8 floats of the 128-dim row.
__global__ __launch_bounds__(256) void k_agg(
    const float* __restrict__ ent, const int* __restrict__ offs,
    const int* __restrict__ cnt, const float* __restrict__ pval,
    const int* __restrict__ tailid, float* __restrict__ agg, int N)
{
    const int lane = threadIdx.x & 15;
    int head = blockIdx.x * 16 + (threadIdx.x >> 4);
    if (head >= N) return;
    int start = offs[head];
    int c     = cnt[head];
    float acc[8] = {0,0,0,0,0,0,0,0};
    float denom = 0.f;
    for (int i = 0; i < c; ++i) {
        float p = pval[start + i];           // same addr across 16 lanes -> broadcast
        int   t = tailid[start + i];
        const float4* pt = (const float4*)(ent + (size_t)t * EMBED) + lane * 2;
        float4 a = pt[0], b = pt[1];
        acc[0] += p * a.x; acc[1] += p * a.y; acc[2] += p * a.z; acc[3] += p * a.w;
        acc[4] += p * b.x; acc[5] += p * b.y; acc[6] += p * b.z; acc[7] += p * b.w;
        denom += p;
    }
    float inv = 1.0f / (denom + 1e-10f);
    float4* dst = (float4*)(agg + (size_t)head * EMBED) + lane * 2;
    dst[0] = make_float4(acc[0] * inv, acc[1] * inv, acc[2] * inv, acc[3] * inv);
    dst[1] = make_float4(acc[4] * inv, acc[5] * inv, acc[6] * inv, acc[7] * inv);
}

// ---------------- K5: out = leaky_relu((ent + agg) @ W^T), fp32 ----------------
__global__ __launch_bounds__(256) void k_gemm(
    const float* __restrict__ ent, const float* __restrict__ W,
    const float* __restrict__ agg, float* __restrict__ out, int N)
{
    __shared__ float Wl[EMBED * EMBED];          // 64 KB: W[j][d] row-major
    for (int i = threadIdx.x; i < EMBED * EMBED; i += 256)
        Wl[i] = W[i];
    __syncthreads();

    int n = blockIdx.x * 256 + threadIdx.x;
    if (n >= N) return;

    float xr[EMBED];
    const float4* pe = (const float4*)(ent + (size_t)n * EMBED);
    const float4* pa = (const float4*)(agg + (size_t)n * EMBED);
    #pragma unroll
    for (int i = 0; i < 32; ++i) {
        float4 a = pe[i], b = pa[i];
        xr[4 * i + 0] = a.x + b.x;
        xr[4 * i + 1] = a.y + b.y;
        xr[4 * i + 2] = a.z + b.z;
        xr[4 * i + 3] = a.w + b.w;
    }
    float* orow = out + (size_t)n * EMBED;
    for (int j = 0; j < EMBED; ++j) {
        const float4* wr = (const float4*)(Wl + j * EMBED);  // wave-uniform -> LDS broadcast
        float acc = 0.f;
        #pragma unroll
        for (int i = 0; i < 32; ++i) {
            float4 w = wr[i];
            acc += xr[4 * i + 0] * w.x + xr[4 * i + 1] * w.y
                 + xr[4 * i + 2] * w.z + xr[4 * i + 3] * w.w;
        }
        orow[j] = (acc > 0.f) ? acc : 0.2f * acc;
    }
}

extern "C" void kernel_launch(void* const* d_in, const int* in_sizes, int n_in,
                              void* d_out, int out_size, void* d_ws, size_t ws_size,
                              hipStream_t stream)
{
    const float* ent   = (const float*)d_in[0];   // entity_emb  [N,128] fp32
    const float* rel   = (const float*)d_in[1];   // rel_embed   [64,128] fp32
    const float* W     = (const float*)d_in[2];   // W           [128,128] fp32
    const int*   heads = (const int*)d_in[3];
    const int*   rels  = (const int*)d_in[4];
    const int*   tails = (const int*)d_in[5];
    const int E = in_sizes[3];
    const int N = in_sizes[0] / EMBED;
    float* out = (float*)d_out;

    // ws layout: agg[N*128]f | score[E]f | pval[E]f | tailid[E]i |
    //            cnt[N]i | offs[N]i | cursor[N]i | blockmax[SBLK]f | M[1]f   (~60 MB)
    float* agg      = (float*)d_ws;
    float* score    = agg + (size_t)N * EMBED;
    float* pval     = score + E;
    int*   tailid   = (int*)(pval + E);
    int*   cnt      = tailid + E;
    int*   offs     = cnt + N;
    int*   cursor   = offs + N;
    float* blockmax = (float*)(cursor + N);
    float* Mval     = blockmax + SBLK;

    hipMemsetAsync(cnt, 0, (size_t)N * sizeof(int), stream);

    k_score<<<SBLK, 256, 0, stream>>>(ent, rel, heads, rels, tails, score, blockmax, cnt, E);
    k_maxred<<<1, 256, 0, stream>>>(blockmax, Mval, SBLK);
    k_scan<<<1, 1024, 0, stream>>>(cnt, offs, cursor, N);
    k_fill<<<(E + 255) / 256, 256, 0, stream>>>(score, heads, tails, Mval, cursor, pval, tailid, E);
    k_agg<<<(N + 15) / 16, 256, 0, stream>>>(ent, offs, cnt, pval, tailid, agg, N);
    k_gemm<<<(N + 255) / 256, 256, 0, stream>>>(ent, W, agg, out, N);
}

// Round 4
// 480.961 us; speedup vs baseline: 3.1117x; 1.4716x over previous
//
#include <hip/hip_runtime.h>
#include <math.h>

#define EMBED 128
#define SBLK 4096    // blocks for edge kernels; blockmax array size
#define LDSPAD 136   // 128 + 8 bf16 pad -> 272 B row stride, bank stride 4 (2-way, free)

typedef __attribute__((ext_vector_type(8))) short short8;
typedef __attribute__((ext_vector_type(4))) short short4v;
typedef __attribute__((ext_vector_type(4))) float floatx4;

__device__ __forceinline__ float fast_tanh(float x) {
    float ax = fabsf(x);
    float e = __expf(-2.0f * ax);         // in (0,1], no overflow
    float t = (1.0f - e) / (1.0f + e);
    return copysignf(t, x);
}

__device__ __forceinline__ unsigned short f2b(float f) {   // fp32 -> bf16 RNE
    union { float f; unsigned int u; } v; v.f = f;
    unsigned int r = v.u + 0x7FFFu + ((v.u >> 16) & 1u);
    return (unsigned short)(r >> 16);
}

// ---------------- K1: per-edge score + per-block max + head histogram ----------------
__global__ __launch_bounds__(256) void k_score(
    const float* __restrict__ ent, const float* __restrict__ rel,
    const int* __restrict__ heads, const int* __restrict__ rels,
    const int* __restrict__ tails,
    float* __restrict__ score, float* __restrict__ blockmax,
    int* __restrict__ cnt, int E)
{
    const int lane  = threadIdx.x & 15;
    const int group = threadIdx.x >> 4;
    int gid    = blockIdx.x * 16 + group;
    int stride = gridDim.x * 16;
    float lmax = -INFINITY;
    for (int e = gid; e < E; e += stride) {
        int h = heads[e], r = rels[e], t = tails[e];
        const float4* ph = (const float4*)(ent + (size_t)h * EMBED) + lane * 2;
        const float4* pt = (const float4*)(ent + (size_t)t * EMBED) + lane * 2;
        const float4* pr = (const float4*)(rel + (size_t)r * EMBED) + lane * 2;
        float s = 0.f;
        #pragma unroll
        for (int q = 0; q < 2; ++q) {
            float4 vh = ph[q], vt = pt[q], vr = pr[q];
            s += vt.x * fast_tanh(vh.x + vr.x);
            s += vt.y * fast_tanh(vh.y + vr.y);
            s += vt.z * fast_tanh(vh.z + vr.z);
            s += vt.w * fast_tanh(vh.w + vr.w);
        }
        s += __shfl_xor(s, 1, 16);
        s += __shfl_xor(s, 2, 16);
        s += __shfl_xor(s, 4, 16);
        s += __shfl_xor(s, 8, 16);
        if (lane == 0) {
            score[e] = s;
            atomicAdd(cnt + h, 1);
        }
        lmax = fmaxf(lmax, s);
    }
    __shared__ float smax[256];
    smax[threadIdx.x] = lmax;
    __syncthreads();
    for (int off = 128; off > 0; off >>= 1) {
        if ((int)threadIdx.x < off)
            smax[threadIdx.x] = fmaxf(smax[threadIdx.x], smax[threadIdx.x + off]);
        __syncthreads();
    }
    if (threadIdx.x == 0) blockmax[blockIdx.x] = smax[0];
}

// ---------------- K1b: reduce blockmax -> M ----------------
__global__ __launch_bounds__(256) void k_maxred(
    const float* __restrict__ blockmax, float* __restrict__ Mout, int n)
{
    __shared__ float smax[256];
    float m = -INFINITY;
    for (int i = threadIdx.x; i < n; i += 256) m = fmaxf(m, blockmax[i]);
    smax[threadIdx.x] = m;
    __syncthreads();
    for (int off = 128; off > 0; off >>= 1) {
        if ((int)threadIdx.x < off)
            smax[threadIdx.x] = fmaxf(smax[threadIdx.x], smax[threadIdx.x + off]);
        __syncthreads();
    }
    if (threadIdx.x == 0) Mout[0] = smax[0];
}

// ---------------- K2: single-block exclusive scan of cnt -> offs, cursor ----------------
__global__ __launch_bounds__(1024) void k_scan(
    const int* __restrict__ cnt, int* __restrict__ offs,
    int* __restrict__ cursor, int N)
{
    __shared__ int buf[1024];
    __shared__ int carry_s;
    if (threadIdx.x == 0) carry_s = 0;
    __syncthreads();
    int nch = (N + 1023) >> 10;
    for (int c = 0; c < nch; ++c) {
        int i = c * 1024 + threadIdx.x;
        int v = (i < N) ? cnt[i] : 0;
        buf[threadIdx.x] = v;
        __syncthreads();
        for (int off = 1; off < 1024; off <<= 1) {
            int x = (threadIdx.x >= (unsigned)off) ? buf[threadIdx.x - off] : 0;
            __syncthreads();
            buf[threadIdx.x] += x;
            __syncthreads();
        }
        int excl = buf[threadIdx.x] - v + carry_s;
        if (i < N) { offs[i] = excl; cursor[i] = excl; }
        __syncthreads();
        if (threadIdx.x == 1023) carry_s += buf[1023];
        __syncthreads();
    }
}

// ---------------- K3: bucket-fill: p = exp(s-M), (p, tail) -> CSR position ----------------
__global__ __launch_bounds__(256) void k_fill(
    const float* __restrict__ score, const int* __restrict__ heads,
    const int* __restrict__ tails, const float* __restrict__ Mptr,
    int* __restrict__ cursor, float* __restrict__ pval,
    int* __restrict__ tailid, int E)
{
    int e = blockIdx.x * 256 + threadIdx.x;
    if (e >= E) return;
    float p = __expf(score[e] - Mptr[0]);
    int pos = atomicAdd(cursor + heads[e], 1);
    pval[pos] = p;
    tailid[pos] = tails[e];
}

// ---------------- K4: per-head gather: agg[h] = (sum p*e_t) / (sum p + 1e-10) ----------------
__global__ __launch_bounds__(256) void k_agg(
    const float* __restrict__ ent, const int* __restrict__ offs,
    const int* __restrict__ cnt, const float* __restrict__ pval,
    const int* __restrict__ tailid, float* __restrict__ agg, int N)
{
    const int lane = threadIdx.x & 15;
    int head = blockIdx.x * 16 + (threadIdx.x >> 4);
    if (head >= N) return;
    int start = offs[head];
    int c     = cnt[head];
    float acc[8] = {0,0,0,0,0,0,0,0};
    float denom = 0.f;
    for (int i = 0; i < c; ++i) {
        float p = pval[start + i];           // same addr across 16 lanes -> broadcast
        int   t = tailid[start + i];
        const float4* pt = (const float4*)(ent + (size_t)t * EMBED) + lane * 2;
        float4 a = pt[0], b = pt[1];
        acc[0] += p * a.x; acc[1] += p * a.y; acc[2] += p * a.z; acc[3] += p * a.w;
        acc[4] += p * b.x; acc[5] += p * b.y; acc[6] += p * b.z; acc[7] += p * b.w;
        denom += p;
    }
    float inv = 1.0f / (denom + 1e-10f);
    float4* dst = (float4*)(agg + (size_t)head * EMBED) + lane * 2;
    dst[0] = make_float4(acc[0] * inv, acc[1] * inv, acc[2] * inv, acc[3] * inv);
    dst[1] = make_float4(acc[4] * inv, acc[5] * inv, acc[6] * inv, acc[7] * inv);
}

// ---------------- K5: out = leaky_relu((ent + agg) @ W^T) via bf16 MFMA ----------------
// Block = 4 waves computes a 128x128 output tile. x = ent+agg cast to bf16 in LDS,
// W cast to bf16 in LDS. A-frag: A[m=lane&15][k=quad*8+j]; B-frag: B[k][n=lane&15],
// k=quad*8+j (reads 8 contiguous bf16 from row n of W, since B[k][n]=W[n][k]).
// C/D: col=lane&15, row=quad*4+reg.
__global__ __launch_bounds__(256) void k_gemm(
    const float* __restrict__ ent, const float* __restrict__ W,
    const float* __restrict__ agg, float* __restrict__ out, int N)
{
    __shared__ short xs[128 * LDSPAD];   // 34 KB
    __shared__ short ws[128 * LDSPAD];   // 34 KB
    const int tid = threadIdx.x;
    const int n0  = blockIdx.x * 128;

    // stage W: 4096 float4, 16 per thread
    #pragma unroll
    for (int it = 0; it < 16; ++it) {
        int f4 = it * 256 + tid;
        int row = f4 >> 5, col4 = f4 & 31;
        float4 v = ((const float4*)W)[f4];
        short4v b; b[0] = (short)f2b(v.x); b[1] = (short)f2b(v.y);
                   b[2] = (short)f2b(v.z); b[3] = (short)f2b(v.w);
        *(short4v*)(ws + row * LDSPAD + col4 * 4) = b;
    }
    // stage x = ent + agg (row-guarded)
    #pragma unroll
    for (int it = 0; it < 16; ++it) {
        int f4 = it * 256 + tid;
        int row = f4 >> 5, col4 = f4 & 31;
        int g = n0 + row;
        float4 a = make_float4(0.f, 0.f, 0.f, 0.f);
        float4 c = a;
        if (g < N) {
            a = ((const float4*)(ent + (size_t)g * EMBED))[col4];
            c = ((const float4*)(agg + (size_t)g * EMBED))[col4];
        }
        short4v b; b[0] = (short)f2b(a.x + c.x); b[1] = (short)f2b(a.y + c.y);
                   b[2] = (short)f2b(a.z + c.z); b[3] = (short)f2b(a.w + c.w);
        *(short4v*)(xs + row * LDSPAD + col4 * 4) = b;
    }
    __syncthreads();

    const int wv   = tid >> 6;       // wave 0..3 -> rows wv*32 .. wv*32+31
    const int lane = tid & 63;
    const int n16  = lane & 15;
    const int quad = lane >> 4;

    floatx4 acc[2][8];
    #pragma unroll
    for (int rt = 0; rt < 2; ++rt)
        #pragma unroll
        for (int jt = 0; jt < 8; ++jt)
            acc[rt][jt] = (floatx4){0.f, 0.f, 0.f, 0.f};

    #pragma unroll
    for (int kc = 0; kc < 4; ++kc) {
        int koff = kc * 32 + quad * 8;
        short8 a0 = *(const short8*)(xs + (wv * 32      + n16) * LDSPAD + koff);
        short8 a1 = *(const short8*)(xs + (wv * 32 + 16 + n16) * LDSPAD + koff);
        #pragma unroll
        for (int jt = 0; jt < 8; ++jt) {
            short8 b = *(const short8*)(ws + (jt * 16 + n16) * LDSPAD + koff);
            acc[0][jt] = __builtin_amdgcn_mfma_f32_16x16x32_bf16(a0, b, acc[0][jt], 0, 0, 0);
            acc[1][jt] = __builtin_amdgcn_mfma_f32_16x16x32_bf16(a1, b, acc[1][jt], 0, 0, 0);
        }
    }

    // epilogue: leaky-relu + store (16 consecutive floats per quad -> 64 B segments)
    #pragma unroll
    for (int rt = 0; rt < 2; ++rt) {
        int rowbase = n0 + wv * 32 + rt * 16 + quad * 4;
        #pragma unroll
        for (int r = 0; r < 4; ++r) {
            int grow = rowbase + r;
            if (grow < N) {
                float* o = out + (size_t)grow * EMBED + n16;
                #pragma unroll
                for (int jt = 0; jt < 8; ++jt) {
                    float v = acc[rt][jt][r];
                    o[jt * 16] = (v > 0.f) ? v : 0.2f * v;
                }
            }
        }
    }
}

extern "C" void kernel_launch(void* const* d_in, const int* in_sizes, int n_in,
                              void* d_out, int out_size, void* d_ws, size_t ws_size,
                              hipStream_t stream)
{
    const float* ent   = (const float*)d_in[0];   // entity_emb  [N,128] fp32
    const float* rel   = (const float*)d_in[1];   // rel_embed   [64,128] fp32
    const float* W     = (const float*)d_in[2];   // W           [128,128] fp32
    const int*   heads = (const int*)d_in[3];
    const int*   rels  = (const int*)d_in[4];
    const int*   tails = (const int*)d_in[5];
    const int E = in_sizes[3];
    const int N = in_sizes[0] / EMBED;
    float* out = (float*)d_out;

    // ws layout: agg[N*128]f | score[E]f | pval[E]f | tailid[E]i |
    //            cnt[N]i | offs[N]i | cursor[N]i | blockmax[SBLK]f | M[1]f
    float* agg      = (float*)d_ws;
    float* score    = agg + (size_t)N * EMBED;
    float* pval     = score + E;
    int*   tailid   = (int*)(pval + E);
    int*   cnt      = tailid + E;
    int*   offs     = cnt + N;
    int*   cursor   = offs + N;
    float* blockmax = (float*)(cursor + N);
    float* Mval     = blockmax + SBLK;

    hipMemsetAsync(cnt, 0, (size_t)N * sizeof(int), stream);

    k_score<<<SBLK, 256, 0, stream>>>(ent, rel, heads, rels, tails, score, blockmax, cnt, E);
    k_maxred<<<1, 256, 0, stream>>>(blockmax, Mval, SBLK);
    k_scan<<<1, 1024, 0, stream>>>(cnt, offs, cursor, N);
    k_fill<<<(E + 255) / 256, 256, 0, stream>>>(score, heads, tails, Mval, cursor, pval, tailid, E);
    k_agg<<<(N + 15) / 16, 256, 0, stream>>>(ent, offs, cnt, pval, tailid, agg, N);
    k_gemm<<<(N + 127) / 128, 256, 0, stream>>>(ent, W, agg, out, N);
}

// Round 5
// 312.250 us; speedup vs baseline: 4.7930x; 1.5403x over previous
//
#include <hip/hip_runtime.h>
#include <math.h>

#define EMBED 128
#define SBLK 4096    // blocks for edge kernels; blockmax array size
#define LDSPAD 136   // 128 + 8 bf16 pad -> 272 B row stride, bank stride 4 (2-way, free)

typedef __attribute__((ext_vector_type(8))) short short8;
typedef __attribute__((ext_vector_type(4))) short short4v;
typedef __attribute__((ext_vector_type(4))) float floatx4;

__device__ __forceinline__ float fast_tanh(float x) {
    float ax = fabsf(x);
    float e = __expf(-2.0f * ax);         // in (0,1], no overflow
    float t = (1.0f - e) / (1.0f + e);
    return copysignf(t, x);
}

__device__ __forceinline__ unsigned short f2b(float f) {   // fp32 -> bf16 RNE
    union { float f; unsigned int u; } v; v.f = f;
    unsigned int r = v.u + 0x7FFFu + ((v.u >> 16) & 1u);
    return (unsigned short)(r >> 16);
}

// ---------------- K1: per-edge score + per-block max + head histogram ----------------
__global__ __launch_bounds__(256) void k_score(
    const float* __restrict__ ent, const float* __restrict__ rel,
    const int* __restrict__ heads, const int* __restrict__ rels,
    const int* __restrict__ tails,
    float* __restrict__ score, float* __restrict__ blockmax,
    int* __restrict__ cnt, int E)
{
    const int lane  = threadIdx.x & 15;
    const int group = threadIdx.x >> 4;
    int gid    = blockIdx.x * 16 + group;
    int stride = gridDim.x * 16;
    float lmax = -INFINITY;
    for (int e = gid; e < E; e += stride) {
        int h = heads[e], r = rels[e], t = tails[e];
        const float4* ph = (const float4*)(ent + (size_t)h * EMBED) + lane * 2;
        const float4* pt = (const float4*)(ent + (size_t)t * EMBED) + lane * 2;
        const float4* pr = (const float4*)(rel + (size_t)r * EMBED) + lane * 2;
        float s = 0.f;
        #pragma unroll
        for (int q = 0; q < 2; ++q) {
            float4 vh = ph[q], vt = pt[q], vr = pr[q];
            s += vt.x * fast_tanh(vh.x + vr.x);
            s += vt.y * fast_tanh(vh.y + vr.y);
            s += vt.z * fast_tanh(vh.z + vr.z);
            s += vt.w * fast_tanh(vh.w + vr.w);
        }
        s += __shfl_xor(s, 1, 16);
        s += __shfl_xor(s, 2, 16);
        s += __shfl_xor(s, 4, 16);
        s += __shfl_xor(s, 8, 16);
        if (lane == 0) {
            score[e] = s;
            atomicAdd(cnt + h, 1);
        }
        lmax = fmaxf(lmax, s);
    }
    __shared__ float smax[256];
    smax[threadIdx.x] = lmax;
    __syncthreads();
    for (int off = 128; off > 0; off >>= 1) {
        if ((int)threadIdx.x < off)
            smax[threadIdx.x] = fmaxf(smax[threadIdx.x], smax[threadIdx.x + off]);
        __syncthreads();
    }
    if (threadIdx.x == 0) blockmax[blockIdx.x] = smax[0];
}

// ---------------- K1b: reduce blockmax -> M ----------------
__global__ __launch_bounds__(256) void k_maxred(
    const float* __restrict__ blockmax, float* __restrict__ Mout, int n)
{
    __shared__ float smax[256];
    float m = -INFINITY;
    for (int i = threadIdx.x; i < n; i += 256) m = fmaxf(m, blockmax[i]);
    smax[threadIdx.x] = m;
    __syncthreads();
    for (int off = 128; off > 0; off >>= 1) {
        if ((int)threadIdx.x < off)
            smax[threadIdx.x] = fmaxf(smax[threadIdx.x], smax[threadIdx.x + off]);
        __syncthreads();
    }
    if (threadIdx.x == 0) Mout[0] = smax[0];
}

// ---------------- K2a: per-block scan (1024-chunk) -> local excl scan + block sum ----------------
__global__ __launch_bounds__(1024) void k_scan1(
    const int* __restrict__ cnt, int* __restrict__ offs,
    int* __restrict__ bsum, int N)
{
    __shared__ int buf[1024];
    int i = blockIdx.x * 1024 + threadIdx.x;
    int v = (i < N) ? cnt[i] : 0;
    buf[threadIdx.x] = v;
    __syncthreads();
    for (int off = 1; off < 1024; off <<= 1) {
        int x = (threadIdx.x >= (unsigned)off) ? buf[threadIdx.x - off] : 0;
        __syncthreads();
        buf[threadIdx.x] += x;
        __syncthreads();
    }
    if (i < N) offs[i] = buf[threadIdx.x] - v;     // exclusive within block
    if (threadIdx.x == 1023) bsum[blockIdx.x] = buf[1023];
}

// ---------------- K2b: scan of block sums (nb <= 1024), in place ----------------
__global__ __launch_bounds__(1024) void k_scan2(int* __restrict__ bsum, int nb)
{
    __shared__ int buf[1024];
    int v = (threadIdx.x < (unsigned)nb) ? bsum[threadIdx.x] : 0;
    buf[threadIdx.x] = v;
    __syncthreads();
    for (int off = 1; off < 1024; off <<= 1) {
        int x = (threadIdx.x >= (unsigned)off) ? buf[threadIdx.x - off] : 0;
        __syncthreads();
        buf[threadIdx.x] += x;
        __syncthreads();
    }
    if (threadIdx.x < (unsigned)nb) bsum[threadIdx.x] = buf[threadIdx.x] - v;
}

// ---------------- K2c: add block offsets -> offs, cursor ----------------
__global__ __launch_bounds__(256) void k_scan3(
    int* __restrict__ offs, const int* __restrict__ bsum,
    int* __restrict__ cursor, int N)
{
    int i = blockIdx.x * 256 + threadIdx.x;
    if (i < N) {
        int o = offs[i] + bsum[i >> 10];
        offs[i] = o;
        cursor[i] = o;
    }
}

// ---------------- K3: bucket-fill: p = exp(s-M), (p, tail) -> CSR position ----------------
__global__ __launch_bounds__(256) void k_fill(
    const float* __restrict__ score, const int* __restrict__ heads,
    const int* __restrict__ tails, const float* __restrict__ Mptr,
    int* __restrict__ cursor, float* __restrict__ pval,
    int* __restrict__ tailid, int E)
{
    int e = blockIdx.x * 256 + threadIdx.x;
    if (e >= E) return;
    float p = __expf(score[e] - Mptr[0]);
    int pos = atomicAdd(cursor + heads[e], 1);
    pval[pos] = p;
    tailid[pos] = tails[e];
}

// ---------------- K4: per-head gather: agg[h] = (sum p*e_t) / (sum p + 1e-10) ----------------
__global__ __launch_bounds__(256) void k_agg(
    const float* __restrict__ ent, const int* __restrict__ offs,
    const int* __restrict__ cnt, const float* __restrict__ pval,
    const int* __restrict__ tailid, float* __restrict__ agg, int N)
{
    const int lane = threadIdx.x & 15;
    int head = blockIdx.x * 16 + (threadIdx.x >> 4);
    if (head >= N) return;
    int start = offs[head];
    int c     = cnt[head];
    float acc[8] = {0,0,0,0,0,0,0,0};
    float denom = 0.f;
    for (int i = 0; i < c; ++i) {
        float p = pval[start + i];           // same addr across 16 lanes -> broadcast
        int   t = tailid[start + i];
        const float4* pt = (const float4*)(ent + (size_t)t * EMBED) + lane * 2;
        float4 a = pt[0], b = pt[1];
        acc[0] += p * a.x; acc[1] += p * a.y; acc[2] += p * a.z; acc[3] += p * a.w;
        acc[4] += p * b.x; acc[5] += p * b.y; acc[6] += p * b.z; acc[7] += p * b.w;
        denom += p;
    }
    float inv = 1.0f / (denom + 1e-10f);
    float4* dst = (float4*)(agg + (size_t)head * EMBED) + lane * 2;
    dst[0] = make_float4(acc[0] * inv, acc[1] * inv, acc[2] * inv, acc[3] * inv);
    dst[1] = make_float4(acc[4] * inv, acc[5] * inv, acc[6] * inv, acc[7] * inv);
}

// ---------------- K5: out = leaky_relu((ent + agg) @ W^T) via bf16 MFMA ----------------
__global__ __launch_bounds__(256) void k_gemm(
    const float* __restrict__ ent, const float* __restrict__ W,
    const float* __restrict__ agg, float* __restrict__ out, int N)
{
    __shared__ short xs[128 * LDSPAD];   // 34 KB
    __shared__ short ws[128 * LDSPAD];   // 34 KB
    const int tid = threadIdx.x;
    const int n0  = blockIdx.x * 128;

    #pragma unroll
    for (int it = 0; it < 16; ++it) {
        int f4 = it * 256 + tid;
        int row = f4 >> 5, col4 = f4 & 31;
        float4 v = ((const float4*)W)[f4];
        short4v b; b[0] = (short)f2b(v.x); b[1] = (short)f2b(v.y);
                   b[2] = (short)f2b(v.z); b[3] = (short)f2b(v.w);
        *(short4v*)(ws + row * LDSPAD + col4 * 4) = b;
    }
    #pragma unroll
    for (int it = 0; it < 16; ++it) {
        int f4 = it * 256 + tid;
        int row = f4 >> 5, col4 = f4 & 31;
        int g = n0 + row;
        float4 a = make_float4(0.f, 0.f, 0.f, 0.f);
        float4 c = a;
        if (g < N) {
            a = ((const float4*)(ent + (size_t)g * EMBED))[col4];
            c = ((const float4*)(agg + (size_t)g * EMBED))[col4];
        }
        short4v b; b[0] = (short)f2b(a.x + c.x); b[1] = (short)f2b(a.y + c.y);
                   b[2] = (short)f2b(a.z + c.z); b[3] = (short)f2b(a.w + c.w);
        *(short4v*)(xs + row * LDSPAD + col4 * 4) = b;
    }
    __syncthreads();

    const int wv   = tid >> 6;
    const int lane = tid & 63;
    const int n16  = lane & 15;
    const int quad = lane >> 4;

    floatx4 acc[2][8];
    #pragma unroll
    for (int rt = 0; rt < 2; ++rt)
        #pragma unroll
        for (int jt = 0; jt < 8; ++jt)
            acc[rt][jt] = (floatx4){0.f, 0.f, 0.f, 0.f};

    #pragma unroll
    for (int kc = 0; kc < 4; ++kc) {
        int koff = kc * 32 + quad * 8;
        short8 a0 = *(const short8*)(xs + (wv * 32      + n16) * LDSPAD + koff);
        short8 a1 = *(const short8*)(xs + (wv * 32 + 16 + n16) * LDSPAD + koff);
        #pragma unroll
        for (int jt = 0; jt < 8; ++jt) {
            short8 b = *(const short8*)(ws + (jt * 16 + n16) * LDSPAD + koff);
            acc[0][jt] = __builtin_amdgcn_mfma_f32_16x16x32_bf16(a0, b, acc[0][jt], 0, 0, 0);
            acc[1][jt] = __builtin_amdgcn_mfma_f32_16x16x32_bf16(a1, b, acc[1][jt], 0, 0, 0);
        }
    }

    #pragma unroll
    for (int rt = 0; rt < 2; ++rt) {
        int rowbase = n0 + wv * 32 + rt * 16 + quad * 4;
        #pragma unroll
        for (int r = 0; r < 4; ++r) {
            int grow = rowbase + r;
            if (grow < N) {
                float* o = out + (size_t)grow * EMBED + n16;
                #pragma unroll
                for (int jt = 0; jt < 8; ++jt) {
                    float v = acc[rt][jt][r];
                    o[jt * 16] = (v > 0.f) ? v : 0.2f * v;
                }
            }
        }
    }
}

extern "C" void kernel_launch(void* const* d_in, const int* in_sizes, int n_in,
                              void* d_out, int out_size, void* d_ws, size_t ws_size,
                              hipStream_t stream)
{
    const float* ent   = (const float*)d_in[0];   // entity_emb  [N,128] fp32
    const float* rel   = (const float*)d_in[1];   // rel_embed   [64,128] fp32
    const float* W     = (const float*)d_in[2];   // W           [128,128] fp32
    const int*   heads = (const int*)d_in[3];
    const int*   rels  = (const int*)d_in[4];
    const int*   tails = (const int*)d_in[5];
    const int E = in_sizes[3];
    const int N = in_sizes[0] / EMBED;
    float* out = (float*)d_out;

    // ws layout: agg[N*128]f | score[E]f | pval[E]f | tailid[E]i |
    //            cnt[N]i | offs[N]i | cursor[N]i | blockmax[SBLK]f | M[1]f | bsum[1024]i
    float* agg      = (float*)d_ws;
    float* score    = agg + (size_t)N * EMBED;
    float* pval     = score + E;
    int*   tailid   = (int*)(pval + E);
    int*   cnt      = tailid + E;
    int*   offs     = cnt + N;
    int*   cursor   = offs + N;
    float* blockmax = (float*)(cursor + N);
    float* Mval     = blockmax + SBLK;
    int*   bsum     = (int*)(Mval + 1);

    const int nb = (N + 1023) >> 10;   // scan blocks (<= 1024)

    hipMemsetAsync(cnt, 0, (size_t)N * sizeof(int), stream);

    k_score<<<SBLK, 256, 0, stream>>>(ent, rel, heads, rels, tails, score, blockmax, cnt, E);
    k_maxred<<<1, 256, 0, stream>>>(blockmax, Mval, SBLK);
    k_scan1<<<nb, 1024, 0, stream>>>(cnt, offs, bsum, N);
    k_scan2<<<1, 1024, 0, stream>>>(bsum, nb);
    k_scan3<<<(N + 255) / 256, 256, 0, stream>>>(offs, bsum, cursor, N);
    k_fill<<<(E + 255) / 256, 256, 0, stream>>>(score, heads, tails, Mval, cursor, pval, tailid, E);
    k_agg<<<(N + 15) / 16, 256, 0, stream>>>(ent, offs, cnt, pval, tailid, agg, N);
    k_gemm<<<(N + 127) / 128, 256, 0, stream>>>(ent, W, agg, out, N);
}

// Round 6
// 284.168 us; speedup vs baseline: 5.2667x; 1.0988x over previous
//
#include <hip/hip_runtime.h>
#include <math.h>

#define EMBED 128
#define SBLK 4096    // blocks for edge kernels; blockmax array size
#define LDSPAD 136   // 128 + 8 bf16 pad -> 272 B row stride, bank stride 4 (2-way, free)

typedef __attribute__((ext_vector_type(8))) short short8;
typedef __attribute__((ext_vector_type(4))) short short4v;
typedef __attribute__((ext_vector_type(4))) float floatx4;

__device__ __forceinline__ float fast_tanh(float x) {      // div-based (fp32 fallback path)
    float ax = fabsf(x);
    float e = __expf(-2.0f * ax);
    float t = (1.0f - e) / (1.0f + e);
    return copysignf(t, x);
}

__device__ __forceinline__ float fast_tanh2(float x) {     // rcp-based: 1 exp + 1 rcp
    float ax = fabsf(x);
    float e = __expf(2.0f * ax);                            // inf for big ax -> rcp=0 -> t=1
    float t = 1.0f - 2.0f * __builtin_amdgcn_rcpf(1.0f + e);
    return copysignf(t, x);
}

__device__ __forceinline__ unsigned short f2b(float f) {   // fp32 -> bf16 RNE
    union { float f; unsigned int u; } v; v.f = f;
    unsigned int r = v.u + 0x7FFFu + ((v.u >> 16) & 1u);
    return (unsigned short)(r >> 16);
}

__device__ __forceinline__ float b2f(short u) {
    union { float f; unsigned int i; } v;
    v.i = ((unsigned int)(unsigned short)u) << 16;
    return v.f;
}

// ---------------- K0: cast entity + rel tables to bf16 ----------------
__global__ __launch_bounds__(256) void k_cast(
    const float* __restrict__ ent, const float* __restrict__ rel,
    short* __restrict__ entb, short* __restrict__ relb, int ngE, int ngR)
{
    int stride = gridDim.x * 256;
    for (int g = blockIdx.x * 256 + threadIdx.x; g < ngE + ngR; g += stride) {
        const float4* src; short* dst;
        if (g < ngE) { src = (const float4*)ent + (size_t)g * 2; dst = entb + (size_t)g * 8; }
        else { int g2 = g - ngE; src = (const float4*)rel + (size_t)g2 * 2; dst = relb + (size_t)g2 * 8; }
        float4 a = src[0], b = src[1];
        short8 o;
        o[0] = (short)f2b(a.x); o[1] = (short)f2b(a.y); o[2] = (short)f2b(a.z); o[3] = (short)f2b(a.w);
        o[4] = (short)f2b(b.x); o[5] = (short)f2b(b.y); o[6] = (short)f2b(b.z); o[7] = (short)f2b(b.w);
        *(short8*)dst = o;
    }
}

// ---------------- K1 (bf16): per-edge score + per-block max + head histogram ----------------
__global__ __launch_bounds__(256) void k_score_bf(
    const short* __restrict__ entb, const short* __restrict__ relb,
    const int* __restrict__ heads, const int* __restrict__ rels,
    const int* __restrict__ tails,
    float* __restrict__ score, float* __restrict__ blockmax,
    int* __restrict__ cnt, int E)
{
    const int lane  = threadIdx.x & 15;
    int gid    = blockIdx.x * 16 + (threadIdx.x >> 4);
    int stride = gridDim.x * 16;
    float lmax = -INFINITY;
    for (int e = gid; e < E; e += stride) {
        int h = heads[e], r = rels[e], t = tails[e];
        short8 vh = *((const short8*)(entb + (size_t)h * EMBED) + lane);
        short8 vt = *((const short8*)(entb + (size_t)t * EMBED) + lane);
        short8 vr = *((const short8*)(relb + (size_t)r * EMBED) + lane);
        float s = 0.f;
        #pragma unroll
        for (int i = 0; i < 8; ++i)
            s += b2f(vt[i]) * fast_tanh2(b2f(vh[i]) + b2f(vr[i]));
        s += __shfl_xor(s, 1, 16);
        s += __shfl_xor(s, 2, 16);
        s += __shfl_xor(s, 4, 16);
        s += __shfl_xor(s, 8, 16);
        if (lane == 0) {
            score[e] = s;
            atomicAdd(cnt + h, 1);
        }
        lmax = fmaxf(lmax, s);
    }
    __shared__ float smax[256];
    smax[threadIdx.x] = lmax;
    __syncthreads();
    for (int off = 128; off > 0; off >>= 1) {
        if ((int)threadIdx.x < off)
            smax[threadIdx.x] = fmaxf(smax[threadIdx.x], smax[threadIdx.x + off]);
        __syncthreads();
    }
    if (threadIdx.x == 0) blockmax[blockIdx.x] = smax[0];
}

// ---------------- K1 (fp32 fallback) ----------------
__global__ __launch_bounds__(256) void k_score(
    const float* __restrict__ ent, const float* __restrict__ rel,
    const int* __restrict__ heads, const int* __restrict__ rels,
    const int* __restrict__ tails,
    float* __restrict__ score, float* __restrict__ blockmax,
    int* __restrict__ cnt, int E)
{
    const int lane  = threadIdx.x & 15;
    int gid    = blockIdx.x * 16 + (threadIdx.x >> 4);
    int stride = gridDim.x * 16;
    float lmax = -INFINITY;
    for (int e = gid; e < E; e += stride) {
        int h = heads[e], r = rels[e], t = tails[e];
        const float4* ph = (const float4*)(ent + (size_t)h * EMBED) + lane * 2;
        const float4* pt = (const float4*)(ent + (size_t)t * EMBED) + lane * 2;
        const float4* pr = (const float4*)(rel + (size_t)r * EMBED) + lane * 2;
        float s = 0.f;
        #pragma unroll
        for (int q = 0; q < 2; ++q) {
            float4 vh = ph[q], vt = pt[q], vr = pr[q];
            s += vt.x * fast_tanh(vh.x + vr.x);
            s += vt.y * fast_tanh(vh.y + vr.y);
            s += vt.z * fast_tanh(vh.z + vr.z);
            s += vt.w * fast_tanh(vh.w + vr.w);
        }
        s += __shfl_xor(s, 1, 16);
        s += __shfl_xor(s, 2, 16);
        s += __shfl_xor(s, 4, 16);
        s += __shfl_xor(s, 8, 16);
        if (lane == 0) { score[e] = s; atomicAdd(cnt + h, 1); }
        lmax = fmaxf(lmax, s);
    }
    __shared__ float smax[256];
    smax[threadIdx.x] = lmax;
    __syncthreads();
    for (int off = 128; off > 0; off >>= 1) {
        if ((int)threadIdx.x < off)
            smax[threadIdx.x] = fmaxf(smax[threadIdx.x], smax[threadIdx.x + off]);
        __syncthreads();
    }
    if (threadIdx.x == 0) blockmax[blockIdx.x] = smax[0];
}

// ---------------- K1b: reduce blockmax -> M ----------------
__global__ __launch_bounds__(256) void k_maxred(
    const float* __restrict__ blockmax, float* __restrict__ Mout, int n)
{
    __shared__ float smax[256];
    float m = -INFINITY;
    for (int i = threadIdx.x; i < n; i += 256) m = fmaxf(m, blockmax[i]);
    smax[threadIdx.x] = m;
    __syncthreads();
    for (int off = 128; off > 0; off >>= 1) {
        if ((int)threadIdx.x < off)
            smax[threadIdx.x] = fmaxf(smax[threadIdx.x], smax[threadIdx.x + off]);
        __syncthreads();
    }
    if (threadIdx.x == 0) Mout[0] = smax[0];
}

// ---------------- K2a/b/c: two-level scan ----------------
__global__ __launch_bounds__(1024) void k_scan1(
    const int* __restrict__ cnt, int* __restrict__ offs,
    int* __restrict__ bsum, int N)
{
    __shared__ int buf[1024];
    int i = blockIdx.x * 1024 + threadIdx.x;
    int v = (i < N) ? cnt[i] : 0;
    buf[threadIdx.x] = v;
    __syncthreads();
    for (int off = 1; off < 1024; off <<= 1) {
        int x = (threadIdx.x >= (unsigned)off) ? buf[threadIdx.x - off] : 0;
        __syncthreads();
        buf[threadIdx.x] += x;
        __syncthreads();
    }
    if (i < N) offs[i] = buf[threadIdx.x] - v;
    if (threadIdx.x == 1023) bsum[blockIdx.x] = buf[1023];
}

__global__ __launch_bounds__(1024) void k_scan2(int* __restrict__ bsum, int nb)
{
    __shared__ int buf[1024];
    int v = (threadIdx.x < (unsigned)nb) ? bsum[threadIdx.x] : 0;
    buf[threadIdx.x] = v;
    __syncthreads();
    for (int off = 1; off < 1024; off <<= 1) {
        int x = (threadIdx.x >= (unsigned)off) ? buf[threadIdx.x - off] : 0;
        __syncthreads();
        buf[threadIdx.x] += x;
        __syncthreads();
    }
    if (threadIdx.x < (unsigned)nb) bsum[threadIdx.x] = buf[threadIdx.x] - v;
}

__global__ __launch_bounds__(256) void k_scan3(
    int* __restrict__ offs, const int* __restrict__ bsum,
    int* __restrict__ cursor, int N)
{
    int i = blockIdx.x * 256 + threadIdx.x;
    if (i < N) {
        int o = offs[i] + bsum[i >> 10];
        offs[i] = o;
        cursor[i] = o;
    }
}

// ---------------- K3: bucket-fill ----------------
__global__ __launch_bounds__(256) void k_fill(
    const float* __restrict__ score, const int* __restrict__ heads,
    const int* __restrict__ tails, const float* __restrict__ Mptr,
    int* __restrict__ cursor, float* __restrict__ pval,
    int* __restrict__ tailid, int E)
{
    int e = blockIdx.x * 256 + threadIdx.x;
    if (e >= E) return;
    float p = __expf(score[e] - Mptr[0]);
    int pos = atomicAdd(cursor + heads[e], 1);
    pval[pos] = p;
    tailid[pos] = tails[e];
}

// ---------------- K4 (bf16): per-head gather with chunked edge-broadcast ----------------
__global__ __launch_bounds__(256) void k_agg_bf(
    const short* __restrict__ entb, const int* __restrict__ offs,
    const int* __restrict__ cnt, const float* __restrict__ pval,
    const int* __restrict__ tailid, float* __restrict__ agg, int N)
{
    const int lane = threadIdx.x & 15;
    int head = blockIdx.x * 16 + (threadIdx.x >> 4);
    if (head >= N) return;
    int start = offs[head];
    int c     = cnt[head];
    float acc[8] = {0,0,0,0,0,0,0,0};
    float denom = 0.f;
    for (int base = 0; base < c; base += 16) {
        int rem = c - base;
        int m   = rem < 16 ? rem : 16;
        float pv = 0.f; int tv = 0;
        if (lane < m) { pv = pval[start + base + lane]; tv = tailid[start + base + lane]; }
        for (int j = 0; j < m; ++j) {
            float p = __shfl(pv, j, 16);
            int   t = __shfl(tv, j, 16);
            short8 v = *((const short8*)(entb + (size_t)t * EMBED) + lane);
            #pragma unroll
            for (int q = 0; q < 8; ++q) acc[q] += p * b2f(v[q]);
            denom += p;
        }
    }
    float inv = 1.0f / (denom + 1e-10f);
    float4* dst = (float4*)(agg + (size_t)head * EMBED) + lane * 2;
    dst[0] = make_float4(acc[0] * inv, acc[1] * inv, acc[2] * inv, acc[3] * inv);
    dst[1] = make_float4(acc[4] * inv, acc[5] * inv, acc[6] * inv, acc[7] * inv);
}

// ---------------- K4 (fp32 fallback) ----------------
__global__ __launch_bounds__(256) void k_agg(
    const float* __restrict__ ent, const int* __restrict__ offs,
    const int* __restrict__ cnt, const float* __restrict__ pval,
    const int* __restrict__ tailid, float* __restrict__ agg, int N)
{
    const int lane = threadIdx.x & 15;
    int head = blockIdx.x * 16 + (threadIdx.x >> 4);
    if (head >= N) return;
    int start = offs[head];
    int c     = cnt[head];
    float acc[8] = {0,0,0,0,0,0,0,0};
    float denom = 0.f;
    for (int i = 0; i < c; ++i) {
        float p = pval[start + i];
        int   t = tailid[start + i];
        const float4* pt = (const float4*)(ent + (size_t)t * EMBED) + lane * 2;
        float4 a = pt[0], b = pt[1];
        acc[0] += p * a.x; acc[1] += p * a.y; acc[2] += p * a.z; acc[3] += p * a.w;
        acc[4] += p * b.x; acc[5] += p * b.y; acc[6] += p * b.z; acc[7] += p * b.w;
        denom += p;
    }
    float inv = 1.0f / (denom + 1e-10f);
    float4* dst = (float4*)(agg + (size_t)head * EMBED) + lane * 2;
    dst[0] = make_float4(acc[0] * inv, acc[1] * inv, acc[2] * inv, acc[3] * inv);
    dst[1] = make_float4(acc[4] * inv, acc[5] * inv, acc[6] * inv, acc[7] * inv);
}

// ---------------- K5: out = leaky_relu((ent + agg) @ W^T) via bf16 MFMA ----------------
__global__ __launch_bounds__(256) void k_gemm(
    const float* __restrict__ ent, const float* __restrict__ W,
    const float* __restrict__ agg, float* __restrict__ out, int N)
{
    __shared__ short xs[128 * LDSPAD];
    __shared__ short ws[128 * LDSPAD];
    const int tid = threadIdx.x;
    const int n0  = blockIdx.x * 128;

    #pragma unroll
    for (int it = 0; it < 16; ++it) {
        int f4 = it * 256 + tid;
        int row = f4 >> 5, col4 = f4 & 31;
        float4 v = ((const float4*)W)[f4];
        short4v b; b[0] = (short)f2b(v.x); b[1] = (short)f2b(v.y);
                   b[2] = (short)f2b(v.z); b[3] = (short)f2b(v.w);
        *(short4v*)(ws + row * LDSPAD + col4 * 4) = b;
    }
    #pragma unroll
    for (int it = 0; it < 16; ++it) {
        int f4 = it * 256 + tid;
        int row = f4 >> 5, col4 = f4 & 31;
        int g = n0 + row;
        float4 a = make_float4(0.f, 0.f, 0.f, 0.f);
        float4 c = a;
        if (g < N) {
            a = ((const float4*)(ent + (size_t)g * EMBED))[col4];
            c = ((const float4*)(agg + (size_t)g * EMBED))[col4];
        }
        short4v b; b[0] = (short)f2b(a.x + c.x); b[1] = (short)f2b(a.y + c.y);
                   b[2] = (short)f2b(a.z + c.z); b[3] = (short)f2b(a.w + c.w);
        *(short4v*)(xs + row * LDSPAD + col4 * 4) = b;
    }
    __syncthreads();

    const int wv   = tid >> 6;
    const int lane = tid & 63;
    const int n16  = lane & 15;
    const int quad = lane >> 4;

    floatx4 acc[2][8];
    #pragma unroll
    for (int rt = 0; rt < 2; ++rt)
        #pragma unroll
        for (int jt = 0; jt < 8; ++jt)
            acc[rt][jt] = (floatx4){0.f, 0.f, 0.f, 0.f};

    #pragma unroll
    for (int kc = 0; kc < 4; ++kc) {
        int koff = kc * 32 + quad * 8;
        short8 a0 = *(const short8*)(xs + (wv * 32      + n16) * LDSPAD + koff);
        short8 a1 = *(const short8*)(xs + (wv * 32 + 16 + n16) * LDSPAD + koff);
        #pragma unroll
        for (int jt = 0; jt < 8; ++jt) {
            short8 b = *(const short8*)(ws + (jt * 16 + n16) * LDSPAD + koff);
            acc[0][jt] = __builtin_amdgcn_mfma_f32_16x16x32_bf16(a0, b, acc[0][jt], 0, 0, 0);
            acc[1][jt] = __builtin_amdgcn_mfma_f32_16x16x32_bf16(a1, b, acc[1][jt], 0, 0, 0);
        }
    }

    #pragma unroll
    for (int rt = 0; rt < 2; ++rt) {
        int rowbase = n0 + wv * 32 + rt * 16 + quad * 4;
        #pragma unroll
        for (int r = 0; r < 4; ++r) {
            int grow = rowbase + r;
            if (grow < N) {
                float* o = out + (size_t)grow * EMBED + n16;
                #pragma unroll
                for (int jt = 0; jt < 8; ++jt) {
                    float v = acc[rt][jt][r];
                    o[jt * 16] = (v > 0.f) ? v : 0.2f * v;
                }
            }
        }
    }
}

extern "C" void kernel_launch(void* const* d_in, const int* in_sizes, int n_in,
                              void* d_out, int out_size, void* d_ws, size_t ws_size,
                              hipStream_t stream)
{
    const float* ent   = (const float*)d_in[0];   // entity_emb  [N,128] fp32
    const float* rel   = (const float*)d_in[1];   // rel_embed   [64,128] fp32
    const float* W     = (const float*)d_in[2];   // W           [128,128] fp32
    const int*   heads = (const int*)d_in[3];
    const int*   rels  = (const int*)d_in[4];
    const int*   tails = (const int*)d_in[5];
    const int E = in_sizes[3];
    const int N = in_sizes[0] / EMBED;
    const int R = in_sizes[1] / EMBED;
    float* out = (float*)d_out;

    // ws layout: agg[N*128]f | score[E]f | pval[E]f | tailid[E]i | cnt[N]i | offs[N]i |
    //            cursor[N]i | blockmax[SBLK]f | M[1]f | bsum[1024]i | entb[N*128]s | relb[R*128]s
    float* agg      = (float*)d_ws;
    float* score    = agg + (size_t)N * EMBED;
    float* pval     = score + E;
    int*   tailid   = (int*)(pval + E);
    int*   cnt      = tailid + E;
    int*   offs     = cnt + N;
    int*   cursor   = offs + N;
    float* blockmax = (float*)(cursor + N);
    float* Mval     = blockmax + SBLK;
    int*   bsum     = (int*)(Mval + 1);
    short* entb     = (short*)(bsum + 1024);
    short* relb     = entb + (size_t)N * EMBED;
    size_t needed   = (size_t)((char*)(relb + (size_t)R * EMBED) - (char*)d_ws);

    const int nb = (N + 1023) >> 10;
    const bool use_bf = (ws_size >= needed);

    hipMemsetAsync(cnt, 0, (size_t)N * sizeof(int), stream);

    if (use_bf) {
        int ngE = N * EMBED / 8, ngR = R * EMBED / 8;
        k_cast<<<2048, 256, 0, stream>>>(ent, rel, entb, relb, ngE, ngR);
        k_score_bf<<<SBLK, 256, 0, stream>>>(entb, relb, heads, rels, tails, score, blockmax, cnt, E);
    } else {
        k_score<<<SBLK, 256, 0, stream>>>(ent, rel, heads, rels, tails, score, blockmax, cnt, E);
    }
    k_maxred<<<1, 256, 0, stream>>>(blockmax, Mval, SBLK);
    k_scan1<<<nb, 1024, 0, stream>>>(cnt, offs, bsum, N);
    k_scan2<<<1, 1024, 0, stream>>>(bsum, nb);
    k_scan3<<<(N + 255) / 256, 256, 0, stream>>>(offs, bsum, cursor, N);
    k_fill<<<(E + 255) / 256, 256, 0, stream>>>(score, heads, tails, Mval, cursor, pval, tailid, E);
    if (use_bf)
        k_agg_bf<<<(N + 15) / 16, 256, 0, stream>>>(entb, offs, cnt, pval, tailid, agg, N);
    else
        k_agg<<<(N + 15) / 16, 256, 0, stream>>>(ent, offs, cnt, pval, tailid, agg, N);
    k_gemm<<<(N + 127) / 128, 256, 0, stream>>>(ent, W, agg, out, N);
}